// Round 18
// baseline (127.586 us; speedup 1.0000x reference)
//
#include <hip/hip_runtime.h>
#include <stdint.h>

#define HH 480
#define WW 640
#define NG 256
#define CF 256
#define FARV 80.0f
#define TILES_X (WW/64)
#define AST 264   // sh_A stride (shorts)
#define BST 136   // h1/h2 stride (shorts)

typedef __attribute__((ext_vector_type(4))) float f32x4;
typedef __attribute__((ext_vector_type(8))) short s16x8;

__device__ __forceinline__ unsigned short f2bf(float f){
  union { float f; unsigned int u; } c; c.f = f;
  unsigned int u = c.u + 0x7fffu + ((c.u >> 16) & 1u);
  return (unsigned short)(u >> 16);
}
__device__ __forceinline__ float bf2f(unsigned short h){
  union { unsigned int u; float f; } c; c.u = ((unsigned int)h) << 16; return c.f;
}

// ---------------- kernel 1a: project + depth-sort (1 block) ----------------
__global__ __launch_bounds__(256) void k_proj(
    const float* __restrict__ means3d,
    const float* __restrict__ opac,
    const float* __restrict__ scales,
    const float* __restrict__ rots,
    const float* __restrict__ camK,
    const float* __restrict__ camP,
    float* __restrict__ wspq,     // [256][12] f32 (3x float4 per gaussian, sorted)
    int* __restrict__ sidx)
{
  __shared__ float keys[NG];
  const int t = threadIdx.x;

  const float fx = camK[0], fy = camK[4];
  const float cx = camK[2], cy = camK[5];
  float Rw[3][3], tw[3];
#pragma unroll
  for (int r=0;r<3;r++){
#pragma unroll
    for (int c=0;c<3;c++) Rw[r][c] = camP[r*4+c];
    tw[r] = camP[r*4+3];
  }

  float mx = means3d[t*3+0], my = means3d[t*3+1], mz = means3d[t*3+2];
  float tcx = Rw[0][0]*mx + Rw[0][1]*my + Rw[0][2]*mz + tw[0];
  float tcy = Rw[1][0]*mx + Rw[1][1]*my + Rw[1][2]*mz + tw[1];
  float tcz = Rw[2][0]*mx + Rw[2][1]*my + Rw[2][2]*mz + tw[2];
  bool valid = tcz > 0.01f;
  float tzs = valid ? tcz : 1.0f;

  float qw = rots[t*4+0], qx = rots[t*4+1];
  float qy = rots[t*4+2], qz = rots[t*4+3];
  float nrm = sqrtf(qw*qw+qx*qx+qy*qy+qz*qz) + 1e-8f;
  qw /= nrm; qx /= nrm; qy /= nrm; qz /= nrm;
  float Rq[3][3];
  {
    float xx=qx*qx, yy=qy*qy, zz=qz*qz;
    float xy=qx*qy, xz=qx*qz, yz=qy*qz;
    float wx=qw*qx, wy=qw*qy, wz=qw*qz;
    Rq[0][0]=1.f-2.f*(yy+zz); Rq[0][1]=2.f*(xy-wz); Rq[0][2]=2.f*(xz+wy);
    Rq[1][0]=2.f*(xy+wz); Rq[1][1]=1.f-2.f*(xx+zz); Rq[1][2]=2.f*(yz-wx);
    Rq[2][0]=2.f*(xz-wy); Rq[2][1]=2.f*(yz+wx); Rq[2][2]=1.f-2.f*(xx+yy);
  }
  float s0 = scales[t*3+0], s1 = scales[t*3+1], s2 = scales[t*3+2];
  float s0s=s0*s0, s1s=s1*s1, s2s=s2*s2;
  float Sig[3][3];
#pragma unroll
  for (int i=0;i<3;i++)
#pragma unroll
    for (int j=0;j<3;j++)
      Sig[i][j] = s0s*Rq[i][0]*Rq[j][0] + s1s*Rq[i][1]*Rq[j][1] + s2s*Rq[i][2]*Rq[j][2];
  float Tm[3][3];
#pragma unroll
  for (int i=0;i<3;i++)
#pragma unroll
    for (int k=0;k<3;k++)
      Tm[i][k] = Rw[i][0]*Sig[0][k] + Rw[i][1]*Sig[1][k] + Rw[i][2]*Sig[2][k];
  float Sc[3][3];
#pragma unroll
  for (int i=0;i<3;i++)
#pragma unroll
    for (int l=0;l<3;l++)
      Sc[i][l] = Tm[i][0]*Rw[l][0] + Tm[i][1]*Rw[l][1] + Tm[i][2]*Rw[l][2];

  float iz = 1.0f / tzs;
  float r00 = fx*iz, r02 = -fx*tcx*iz*iz;
  float r11 = fy*iz, r12 = -fy*tcy*iz*iz;
  float v0 = Sc[0][0]*r00 + Sc[2][0]*r02;
  float v2 = Sc[0][2]*r00 + Sc[2][2]*r02;
  float v1 = Sc[0][1]*r00 + Sc[2][1]*r02;
  float a  = r00*v0 + r02*v2 + 0.3f;
  float bb = r11*v1 + r12*v2;
  float cc = r11*(Sc[1][1]*r11 + Sc[1][2]*r12) + r12*(Sc[2][1]*r11 + Sc[2][2]*r12) + 0.3f;
  float det = a*cc - bb*bb;
  float inv_det = 1.0f / fmaxf(det, 1e-12f);
  float Av = cc*inv_det, Bv = -bb*inv_det, Cv = a*inv_det;
  float u = fx*tcx*iz + cx;
  float v = fy*tcy*iz + cy;
  float op = opac[t];
  float op_eff = valid ? op : 0.0f;
  float tzo = valid ? tcz : 0.0f;
  float rx = -1.0f, ry = -1.0f;
  if (op_eff > (1.0f/255.0f)){
    float tau = logf(255.0f*op_eff);
    if (tau > 0.0f){
      rx = sqrtf(2.0f*tau*a) + 0.5f;
      ry = sqrtf(2.0f*tau*cc) + 0.5f;
    }
  }
  float key = valid ? tcz : __builtin_inff();

  keys[t] = key;
  __syncthreads();
  int rank = 0;
  for (int j=0;j<NG;j++){
    float kj = keys[j];
    rank += (kj < key) || (kj == key && j < t);
  }
  float4* wq = (float4*)wspq;
  float4 q0; q0.x = u;       q0.y = v;  q0.z = rx;       q0.w = ry;
  float4 q1; q1.x = 0.5f*Av; q1.y = Bv; q1.z = 0.5f*Cv;  q1.w = op_eff;
  float4 q2; q2.x = tzo;     q2.y = 0.f; q2.z = 0.f;     q2.w = 0.f;
  wq[rank*3+0] = q0;
  wq[rank*3+1] = q1;
  wq[rank*3+2] = q2;
  sidx[rank] = t;
}

// ---------------- kernel 1b: gather feats + wt2/wt3 transposes + G1 = F @ w1 (329 blocks) ----------------
__global__ __launch_bounds__(256) void k_gather(
    const float* __restrict__ features,
    const float* __restrict__ w1,
    const float* __restrict__ w2,
    const float* __restrict__ w3,
    const int* __restrict__ sidx,
    unsigned short* __restrict__ wsf,
    unsigned short* __restrict__ wsg1,
    unsigned short* __restrict__ wt2,
    unsigned short* __restrict__ wt3)
{
  const int bx = blockIdx.x, t = threadIdx.x;
  if (bx < 64){
    int c = bx*256 + t;
    int row = c >> 6, c4 = c & 63;
    int src = sidx[row];
    float4 f = ((const float4*)features)[src*(CF/4) + c4];
    unsigned int* dst = (unsigned int*)(wsf + row*CF + c4*4);
    dst[0] = (unsigned)f2bf(f.x) | ((unsigned)f2bf(f.y) << 16);
    dst[1] = (unsigned)f2bf(f.z) | ((unsigned)f2bf(f.w) << 16);
  } else if (bx < 72){
    int base = (bx-64)*2048 + t*8;
#pragma unroll
    for (int e=0;e<8;e++){
      int d = base + e;
      int j = d >> 7, k = d & 127;
      wt2[d] = f2bf(w2[k*128 + j]);
    }
  } else if (bx < 73){
    int base = t*8;
#pragma unroll
    for (int e=0;e<8;e++){
      int d = base + e;
      int j = d >> 7, k = d & 127;
      wt3[d] = (j < 12) ? f2bf(w3[k*12 + j]) : (unsigned short)0;
    }
  } else {
    // G1[g][j] = sum_k F_sorted[g][k] * w1[k][j]  (g = bx-73, j = t<128)
    __shared__ float frow[CF];
    int g = bx - 73;
    int src = sidx[g];
    if (t < 64) ((float4*)frow)[t] = ((const float4*)features)[src*(CF/4) + t];
    __syncthreads();
    if (t < 128){
      float s = 0.0f;
      for (int k=0;k<CF;k++)
        s += frow[k] * w1[k*128 + t];
      wsg1[g*128 + t] = f2bf(s);
    }
  }
}

// ---------------- kernel 2A: render = frontend + splat + rendered store + depth ----------------
__global__ __launch_bounds__(256) void k_render(
    const float* __restrict__ wspq,
    const unsigned short* __restrict__ wsf,
    float* __restrict__ out,
    float* __restrict__ dep)
{
  __shared__ __align__(16) unsigned char smem[64*AST*2 + 17408 + 1296];
  unsigned short* sh_A = (unsigned short*)smem;
  unsigned char* X = smem + 64*AST*2;
  float* c_u    = (float*)X;
  float* c_v    = c_u + 256;
  float* c_hA   = c_u + 512;
  float* c_Bq   = c_u + 768;
  float* c_hC   = c_u + 1024;
  float* c_op   = c_u + 1280;
  float* c_tz   = c_u + 1536;
  float* chprod = c_u + 1792;
  unsigned short* stage = (unsigned short*)X;
  unsigned char* tail = smem + 64*AST*2 + 17408;
  float* depch = (float*)tail;
  unsigned char* act_idx = tail + 1024;
  int* wcnt = (int*)(tail + 1280);

  const int t = threadIdx.x;
  const int lane = t & 63;
  const int wvi = t >> 6;
  const int y  = blockIdx.x / TILES_X;
  const int x0 = (blockIdx.x % TILES_X) * 64;

  act_idx[t] = 0;
  const float4* wq = (const float4*)wspq;
  float4 q0 = wq[t*3+0];
  bool pred = (q0.z > 0.0f)
      && (q0.x + q0.z >= (float)x0 + 0.5f)
      && (q0.x - q0.z <= (float)x0 + 63.5f)
      && (fabsf(q0.y - ((float)y + 0.5f)) <= q0.w);
  unsigned long long m = __ballot(pred);
  if (lane == 0) wcnt[wvi] = __popcll(m);
  __syncthreads();
  int base = 0;
#pragma unroll
  for (int i=0;i<4;i++) base += (i < wvi) ? wcnt[i] : 0;
  const int nact = wcnt[0]+wcnt[1]+wcnt[2]+wcnt[3];
  if (pred){
    int pos = base + __popcll(m & ((1ull << lane) - 1ull));
    float4 q1 = wq[t*3+1];
    float4 q2 = wq[t*3+2];
    act_idx[pos] = (unsigned char)t;
    c_u[pos]  = q0.x;  c_v[pos]  = q0.y;
    c_hA[pos] = q1.x;  c_Bq[pos] = q1.y;  c_hC[pos] = q1.z;
    c_op[pos] = q1.w;  c_tz[pos] = q2.x;
  }
  __syncthreads();

  const int per8 = ((((nact + 3) >> 2) + 7) & ~7);
  const int n0 = wvi * per8;
  const int n1 = (nact < n0 + per8) ? nact : (n0 + per8);
  const float px = (float)(x0 + lane) + 0.5f;
  const float py = (float)y + 0.5f;

  const int ln  = lane & 15;
  const int kq8 = (lane >> 4) * 8;
  const int rq  = (lane >> 4) * 4;
  const int cb0 = wvi * 64;
  const int la = lane & 7, lb = lane >> 3;
  const int kchunks = (nact + 31) >> 5;

  uint4 cur[4], nxt[4];
  if (kchunks > 0){
#pragma unroll
    for (int g=0; g<4; g++){
      int kk = lb + 8*g;
      cur[g] = *(const uint4*)(wsf + (int)act_idx[kk]*CF + cb0 + la*8);
    }
  }

  {
    float prod = 1.0f;
    for (int ng = n0; ng < n0 + per8; ng += 8){
      union { unsigned short s[8]; uint4 v4; } alp;
#pragma unroll
      for (int e=0;e<8;e++){
        int n = ng + e;
        float al = 0.0f;
        if (n < n1){
          float dx = px - c_u[n], dy = py - c_v[n];
          float q = c_hA[n]*dx*dx + c_Bq[n]*dx*dy + c_hC[n]*dy*dy;
          al = fminf(0.99f, c_op[n]*__expf(fminf(-q, 0.0f)));
          if (al < (1.0f/255.0f)) al = 0.0f;
        }
        alp.s[e] = f2bf(al);
        prod *= 1.0f - bf2f(alp.s[e]);
      }
      *((uint4*)&sh_A[lane*AST + ng]) = alp.v4;
    }
    chprod[t] = prod;
  }
  __syncthreads();

  {
    float T = 1.0f;
#pragma unroll
    for (int c=0;c<4;c++) if (c < wvi) T *= chprod[c*64 + lane];
    float dacc = 0.0f;
    for (int ng = n0; ng < n0 + per8; ng += 8){
      union { unsigned short s[8]; uint4 v4; } ap, wp;
      ap.v4 = *((const uint4*)&sh_A[lane*AST + ng]);
#pragma unroll
      for (int e=0;e<8;e++){
        float al = bf2f(ap.s[e]);
        float wgt = T * al;
        T *= 1.0f - al;
        wp.s[e] = f2bf(wgt);
        int n = ng + e;
        if (n < n1) dacc += wgt * c_tz[n];
      }
      *((uint4*)&sh_A[lane*AST + ng]) = wp.v4;
    }
    depch[t] = dacc;
  }
  __syncthreads();

  unsigned short* stW = stage + wvi*2048;
  const int xw = (la & 3) << 3;

  f32x4 acc[4][4];
#pragma unroll
  for (int mt=0;mt<4;mt++)
#pragma unroll
    for (int nt=0;nt<4;nt++){
      f32x4 z = {0.f,0.f,0.f,0.f};
      acc[mt][nt] = z;
    }
  for (int kb=0; kb<kchunks; kb++){
#pragma unroll
    for (int g=0; g<4; g++){
      const unsigned short* s = (const unsigned short*)&cur[g];
      int colw = (lb + 8*g) ^ xw;
#pragma unroll
      for (int i=0;i<8;i++)
        stW[(la*8 + i)*32 + colw] = s[i];
    }
    if (kb+1 < kchunks){
#pragma unroll
      for (int g=0; g<4; g++){
        int kk = (kb+1)*32 + lb + 8*g;
        nxt[g] = *(const uint4*)(wsf + (int)act_idx[kk]*CF + cb0 + la*8);
      }
    }
    int k0 = kb*32;
    s16x8 bfr[4];
#pragma unroll
    for (int nt=0;nt<4;nt++){
      int chl = nt*16 + ln;
      int colr = kq8 ^ (((chl >> 3) & 3) << 3);
      bfr[nt] = *(const s16x8*)(stW + chl*32 + colr);
    }
#pragma unroll
    for (int mt=0;mt<4;mt++){
      s16x8 afr = *(const s16x8*)(&sh_A[(mt*16 + ln)*AST + k0 + kq8]);
#pragma unroll
      for (int nt=0;nt<4;nt++)
        acc[mt][nt] = __builtin_amdgcn_mfma_f32_16x16x32_bf16(afr, bfr[nt], acc[mt][nt], 0, 0, 0);
    }
    if (kb+1 < kchunks){
#pragma unroll
      for (int g=0; g<4; g++) cur[g] = nxt[g];
    }
  }
  __syncthreads();

#pragma unroll
  for (int mt=0;mt<4;mt++)
#pragma unroll
    for (int nt=0;nt<4;nt++)
#pragma unroll
      for (int r=0;r<4;r++){
        int row = mt*16 + rq + r;
        int col = cb0 + nt*16 + ln;
        sh_A[row*AST + col] = f2bf(acc[mt][nt][r]);
      }
  __syncthreads();

  const size_t Pbase = (size_t)(y*WW + x0);
  if (wvi == 0){
    float d = depch[lane] + depch[64+lane] + depch[128+lane] + depch[192+lane];
    dep[y*WW + x0 + lane] = fminf(fmaxf(d, 0.0f), FARV);
  }
  {
    const int pxb = wvi*16;
    for (int i=0;i<16;i++){
      int pix = pxb + i;
      uint2 dv = *(const uint2*)(&sh_A[pix*AST + lane*4]);
      f32x4 o;
      o[0] = bf2f((unsigned short)(dv.x & 0xffffu));
      o[1] = bf2f((unsigned short)(dv.x >> 16));
      o[2] = bf2f((unsigned short)(dv.y & 0xffffu));
      o[3] = bf2f((unsigned short)(dv.y >> 16));
      __builtin_nontemporal_store(o, (f32x4*)(&out[(Pbase + pix)*CF + lane*4]));
    }
  }
}

// ---------------- kernel 2B: seg = frontend + (wgt @ G1) + L2 + L3 ----------------
__global__ __launch_bounds__(256) void k_seg(
    const float* __restrict__ wspq,
    const unsigned short* __restrict__ wsg1,
    const unsigned short* __restrict__ wt2,
    const unsigned short* __restrict__ wt3,
    const float* __restrict__ b1,
    const float* __restrict__ b2,
    const float* __restrict__ b3,
    float* __restrict__ seg)
{
  __shared__ __align__(16) unsigned char smem[64*AST*2 + 17408 + 288];
  unsigned short* sh_A = (unsigned short*)smem;
  unsigned char* X = smem + 64*AST*2;
  float* c_u    = (float*)X;
  float* c_v    = c_u + 256;
  float* c_hA   = c_u + 512;
  float* c_Bq   = c_u + 768;
  float* c_hC   = c_u + 1024;
  float* c_op   = c_u + 1280;
  float* chprod = c_u + 1536;
  unsigned short* stage = (unsigned short*)X;   // K-loop: 4 waves x [32][40]
  unsigned short* sh_B  = (unsigned short*)X;   // h1 -> h2 [64][BST]
  unsigned char* tail = smem + 64*AST*2 + 17408;
  unsigned char* act_idx = tail;                // [256] u8
  int* wcnt = (int*)(tail + 256);               // [4]

  const int t = threadIdx.x;
  const int lane = t & 63;
  const int wvi = t >> 6;
  const int y  = blockIdx.x / TILES_X;
  const int x0 = (blockIdx.x % TILES_X) * 64;

  act_idx[t] = 0;
  const float4* wq = (const float4*)wspq;
  float4 q0 = wq[t*3+0];
  bool pred = (q0.z > 0.0f)
      && (q0.x + q0.z >= (float)x0 + 0.5f)
      && (q0.x - q0.z <= (float)x0 + 63.5f)
      && (fabsf(q0.y - ((float)y + 0.5f)) <= q0.w);
  unsigned long long m = __ballot(pred);
  if (lane == 0) wcnt[wvi] = __popcll(m);
  __syncthreads();
  int base = 0;
#pragma unroll
  for (int i=0;i<4;i++) base += (i < wvi) ? wcnt[i] : 0;
  const int nact = wcnt[0]+wcnt[1]+wcnt[2]+wcnt[3];
  if (pred){
    int pos = base + __popcll(m & ((1ull << lane) - 1ull));
    float4 q1 = wq[t*3+1];
    act_idx[pos] = (unsigned char)t;
    c_u[pos]  = q0.x;  c_v[pos]  = q0.y;
    c_hA[pos] = q1.x;  c_Bq[pos] = q1.y;  c_hC[pos] = q1.z;
    c_op[pos] = q1.w;
  }
  __syncthreads();

  const int per8 = ((((nact + 3) >> 2) + 7) & ~7);
  const int n0 = wvi * per8;
  const int n1 = (nact < n0 + per8) ? nact : (n0 + per8);
  const float px = (float)(x0 + lane) + 0.5f;
  const float py = (float)y + 0.5f;

  const int ln  = lane & 15;
  const int kq8 = (lane >> 4) * 8;
  const int rq  = (lane >> 4) * 4;
  const int rG = lane >> 1, hcG = lane & 1;
  const int kchunks = (nact + 31) >> 5;
  const int n0m = wvi * 32;

  // ---- phase 1: alphas -> bf16 into sh_A; per-chunk products ----
  {
    float prod = 1.0f;
    for (int ng = n0; ng < n0 + per8; ng += 8){
      union { unsigned short s[8]; uint4 v4; } alp;
#pragma unroll
      for (int e=0;e<8;e++){
        int n = ng + e;
        float al = 0.0f;
        if (n < n1){
          float dx = px - c_u[n], dy = py - c_v[n];
          float q = c_hA[n]*dx*dx + c_Bq[n]*dx*dy + c_hC[n]*dy*dy;
          al = fminf(0.99f, c_op[n]*__expf(fminf(-q, 0.0f)));
          if (al < (1.0f/255.0f)) al = 0.0f;
        }
        alp.s[e] = f2bf(al);
        prod *= 1.0f - bf2f(alp.s[e]);
      }
      *((uint4*)&sh_A[lane*AST + ng]) = alp.v4;
    }
    chprod[t] = prod;
  }
  __syncthreads();

  // ---- phase 2: prefix T -> weights bf16 (no depth here) ----
  {
    float T = 1.0f;
#pragma unroll
    for (int c=0;c<4;c++) if (c < wvi) T *= chprod[c*64 + lane];
    for (int ng = n0; ng < n0 + per8; ng += 8){
      union { unsigned short s[8]; uint4 v4; } ap, wp;
      ap.v4 = *((const uint4*)&sh_A[lane*AST + ng]);
#pragma unroll
      for (int e=0;e<8;e++){
        float al = bf2f(ap.s[e]);
        wp.s[e] = f2bf(T * al);
        T *= 1.0f - al;
      }
      *((uint4*)&sh_A[lane*AST + ng]) = wp.v4;
    }
  }
  __syncthreads();

  unsigned short* stW = stage + wvi*1280;   // wave-private [32col][40]

  // ---- h1_pre = wgt @ G1 (per-wave 32-col block) ----
  f32x4 acc1[4][2];
#pragma unroll
  for (int nn=0;nn<2;nn++){
    float bv = b1[n0m + nn*16 + ln];
    f32x4 b4 = {bv,bv,bv,bv};
#pragma unroll
    for (int mt=0;mt<4;mt++) acc1[mt][nn] = b4;
  }
  uint4 ga, gb, ga2, gb2;
  if (kchunks > 0){
    const unsigned short* gsrc = wsg1 + (int)act_idx[rG]*128 + n0m + hcG*16;
    ga = *(const uint4*)gsrc;
    gb = *(const uint4*)(gsrc + 8);
  }
  for (int kb=0; kb<kchunks; kb++){
    // stage G1 chunk
    {
      const unsigned short* gap = (const unsigned short*)&ga;
      const unsigned short* gbp = (const unsigned short*)&gb;
#pragma unroll
      for (int c2=0;c2<8;c2++)
        stW[(hcG*16 + c2)*40 + rG] = gap[c2];
#pragma unroll
      for (int c2=0;c2<8;c2++)
        stW[(hcG*16 + 8 + c2)*40 + rG] = gbp[c2];
    }
    if (kb+1 < kchunks){
      const unsigned short* gsrc = wsg1 + (int)act_idx[(kb+1)*32 + rG]*128 + n0m + hcG*16;
      ga2 = *(const uint4*)gsrc;
      gb2 = *(const uint4*)(gsrc + 8);
    }
    int k0 = kb*32;
    s16x8 bfrG[2];
#pragma unroll
    for (int nt2=0;nt2<2;nt2++)
      bfrG[nt2] = *(const s16x8*)(stW + (nt2*16 + ln)*40 + kq8);
#pragma unroll
    for (int mt=0;mt<4;mt++){
      s16x8 afr = *(const s16x8*)(&sh_A[(mt*16 + ln)*AST + k0 + kq8]);
#pragma unroll
      for (int nt2=0;nt2<2;nt2++)
        acc1[mt][nt2] = __builtin_amdgcn_mfma_f32_16x16x32_bf16(afr, bfrG[nt2], acc1[mt][nt2], 0, 0, 0);
    }
    if (kb+1 < kchunks){ ga = ga2; gb = gb2; }
  }
  __syncthreads();   // all waves done with sh_A + stage

  // ---- h1 relu bf16 -> sh_B ----
#pragma unroll
  for (int mt=0;mt<4;mt++)
#pragma unroll
    for (int nn=0;nn<2;nn++)
#pragma unroll
      for (int r=0;r<4;r++){
        int mrow = mt*16 + rq + r;
        int ncol = n0m + nn*16 + ln;
        sh_B[mrow*BST + ncol] = f2bf(fmaxf(acc1[mt][nn][r], 0.0f));
      }
  __syncthreads();

  // ---- L2 ----
  f32x4 acc2[4][2];
#pragma unroll
  for (int nn=0;nn<2;nn++){
    float bv = b2[n0m + nn*16 + ln];
    f32x4 b4 = {bv,bv,bv,bv};
#pragma unroll
    for (int mt=0;mt<4;mt++) acc2[mt][nn] = b4;
  }
#pragma unroll
  for (int k0=0;k0<128;k0+=32){
    s16x8 bfr0 = *(const s16x8*)(wt2 + (n0m + 0*16 + ln)*128 + k0 + kq8);
    s16x8 bfr1 = *(const s16x8*)(wt2 + (n0m + 1*16 + ln)*128 + k0 + kq8);
#pragma unroll
    for (int mt=0;mt<4;mt++){
      s16x8 afr = *(const s16x8*)(&sh_B[(mt*16 + ln)*BST + k0 + kq8]);
      acc2[mt][0] = __builtin_amdgcn_mfma_f32_16x16x32_bf16(afr, bfr0, acc2[mt][0], 0, 0, 0);
      acc2[mt][1] = __builtin_amdgcn_mfma_f32_16x16x32_bf16(afr, bfr1, acc2[mt][1], 0, 0, 0);
    }
  }
  __syncthreads();
#pragma unroll
  for (int mt=0;mt<4;mt++)
#pragma unroll
    for (int nn=0;nn<2;nn++)
#pragma unroll
      for (int r=0;r<4;r++){
        int mrow = mt*16 + rq + r;
        int ncol = n0m + nn*16 + ln;
        sh_B[mrow*BST + ncol] = f2bf(fmaxf(acc2[mt][nn][r], 0.0f));
      }
  __syncthreads();

  // ---- L3 + seg ----
  const size_t Pbase = (size_t)(y*WW + x0);
  f32x4 acc3;
  {
    float bv = (ln < 12) ? b3[ln] : 0.0f;
    f32x4 b4 = {bv,bv,bv,bv};
    acc3 = b4;
  }
#pragma unroll
  for (int k0=0;k0<128;k0+=32){
    s16x8 afr = *(const s16x8*)(&sh_B[(wvi*16 + ln)*BST + k0 + kq8]);
    s16x8 bfr = *(const s16x8*)(wt3 + ln*128 + k0 + kq8);
    acc3 = __builtin_amdgcn_mfma_f32_16x16x32_bf16(afr, bfr, acc3, 0, 0, 0);
  }
  if (ln < 12){
#pragma unroll
    for (int r=0;r<4;r++){
      int mrow = wvi*16 + rq + r;
      seg[(Pbase + mrow)*12 + ln] = acc3[r];
    }
  }
}

extern "C" void kernel_launch(void* const* d_in, const int* in_sizes, int n_in,
                              void* d_out, int out_size, void* d_ws, size_t ws_size,
                              hipStream_t stream) {
  (void)in_sizes; (void)n_in; (void)out_size; (void)ws_size;
  const float* means3d  = (const float*)d_in[0];
  const float* features = (const float*)d_in[1];
  const float* opac     = (const float*)d_in[2];
  const float* scales   = (const float*)d_in[3];
  const float* rots     = (const float*)d_in[4];
  const float* camK     = (const float*)d_in[5];
  const float* camP     = (const float*)d_in[6];
  const float* w1       = (const float*)d_in[7];
  const float* b1       = (const float*)d_in[8];
  const float* w2       = (const float*)d_in[9];
  const float* b2       = (const float*)d_in[10];
  const float* w3       = (const float*)d_in[11];
  const float* b3       = (const float*)d_in[12];

  char* ws = (char*)d_ws;
  float*          wspq = (float*)ws;                       // [256][12] f32 = 12288 B
  int*            sidx = (int*)(ws + 12288);               // 1024 B
  unsigned short* wsf  = (unsigned short*)(ws + 13312);    // sorted feats [g][ch] bf16 = 131072 B
  unsigned short* wsg1 = (unsigned short*)(ws + 144384);   // G1 = F@w1 sorted [g][128] bf16 = 65536 B
  unsigned short* wt2  = (unsigned short*)(ws + 209920);   // 128x128 bf16 = 32768 B
  unsigned short* wt3  = (unsigned short*)(ws + 242688);   // 16x128 bf16 = 4096 B

  float* out = (float*)d_out;
  float* dep = out + (size_t)HH*WW*CF;
  float* seg = dep + (size_t)HH*WW;

  k_proj<<<1, 256, 0, stream>>>(means3d, opac, scales, rots, camK, camP, wspq, sidx);
  k_gather<<<329, 256, 0, stream>>>(features, w1, w2, w3, sidx, wsf, wsg1, wt2, wt3);
  k_seg<<<HH*TILES_X, 256, 0, stream>>>(wspq, wsg1, wt2, wt3, b1, b2, b3, seg);
  k_render<<<HH*TILES_X, 256, 0, stream>>>(wspq, wsf, out, dep);
}

// Round 19
// 112.748 us; speedup vs baseline: 1.1316x; 1.1316x over previous
//
#include <hip/hip_runtime.h>
#include <stdint.h>

#define HH 480
#define WW 640
#define NG 256
#define CF 256
#define FARV 80.0f
#define TILES_X (WW/64)
#define AST 264   // sh_A stride (shorts)
#define BST 136   // sh_B / h1 / h2 stride (shorts)

typedef __attribute__((ext_vector_type(4))) float f32x4;
typedef __attribute__((ext_vector_type(8))) short s16x8;

__device__ __forceinline__ unsigned short f2bf(float f){
  union { float f; unsigned int u; } c; c.f = f;
  unsigned int u = c.u + 0x7fffu + ((c.u >> 16) & 1u);
  return (unsigned short)(u >> 16);
}
__device__ __forceinline__ float bf2f(unsigned short h){
  union { unsigned int u; float f; } c; c.u = ((unsigned int)h) << 16; return c.f;
}

// ---------------- kernel 1a: project + depth-sort (1 block) ----------------
__global__ __launch_bounds__(256) void k_proj(
    const float* __restrict__ means3d,
    const float* __restrict__ opac,
    const float* __restrict__ scales,
    const float* __restrict__ rots,
    const float* __restrict__ camK,
    const float* __restrict__ camP,
    float* __restrict__ wspq,     // [256][12] f32 (3x float4 per gaussian, sorted)
    int* __restrict__ sidx)
{
  __shared__ float keys[NG];
  const int t = threadIdx.x;

  const float fx = camK[0], fy = camK[4];
  const float cx = camK[2], cy = camK[5];
  float Rw[3][3], tw[3];
#pragma unroll
  for (int r=0;r<3;r++){
#pragma unroll
    for (int c=0;c<3;c++) Rw[r][c] = camP[r*4+c];
    tw[r] = camP[r*4+3];
  }

  float mx = means3d[t*3+0], my = means3d[t*3+1], mz = means3d[t*3+2];
  float tcx = Rw[0][0]*mx + Rw[0][1]*my + Rw[0][2]*mz + tw[0];
  float tcy = Rw[1][0]*mx + Rw[1][1]*my + Rw[1][2]*mz + tw[1];
  float tcz = Rw[2][0]*mx + Rw[2][1]*my + Rw[2][2]*mz + tw[2];
  bool valid = tcz > 0.01f;
  float tzs = valid ? tcz : 1.0f;

  float qw = rots[t*4+0], qx = rots[t*4+1];
  float qy = rots[t*4+2], qz = rots[t*4+3];
  float nrm = sqrtf(qw*qw+qx*qx+qy*qy+qz*qz) + 1e-8f;
  qw /= nrm; qx /= nrm; qy /= nrm; qz /= nrm;
  float Rq[3][3];
  {
    float xx=qx*qx, yy=qy*qy, zz=qz*qz;
    float xy=qx*qy, xz=qx*qz, yz=qy*qz;
    float wx=qw*qx, wy=qw*qy, wz=qw*qz;
    Rq[0][0]=1.f-2.f*(yy+zz); Rq[0][1]=2.f*(xy-wz); Rq[0][2]=2.f*(xz+wy);
    Rq[1][0]=2.f*(xy+wz); Rq[1][1]=1.f-2.f*(xx+zz); Rq[1][2]=2.f*(yz-wx);
    Rq[2][0]=2.f*(xz-wy); Rq[2][1]=2.f*(yz+wx); Rq[2][2]=1.f-2.f*(xx+yy);
  }
  float s0 = scales[t*3+0], s1 = scales[t*3+1], s2 = scales[t*3+2];
  float s0s=s0*s0, s1s=s1*s1, s2s=s2*s2;
  float Sig[3][3];
#pragma unroll
  for (int i=0;i<3;i++)
#pragma unroll
    for (int j=0;j<3;j++)
      Sig[i][j] = s0s*Rq[i][0]*Rq[j][0] + s1s*Rq[i][1]*Rq[j][1] + s2s*Rq[i][2]*Rq[j][2];
  float Tm[3][3];
#pragma unroll
  for (int i=0;i<3;i++)
#pragma unroll
    for (int k=0;k<3;k++)
      Tm[i][k] = Rw[i][0]*Sig[0][k] + Rw[i][1]*Sig[1][k] + Rw[i][2]*Sig[2][k];
  float Sc[3][3];
#pragma unroll
  for (int i=0;i<3;i++)
#pragma unroll
    for (int l=0;l<3;l++)
      Sc[i][l] = Tm[i][0]*Rw[l][0] + Tm[i][1]*Rw[l][1] + Tm[i][2]*Rw[l][2];

  float iz = 1.0f / tzs;
  float r00 = fx*iz, r02 = -fx*tcx*iz*iz;
  float r11 = fy*iz, r12 = -fy*tcy*iz*iz;
  float v0 = Sc[0][0]*r00 + Sc[2][0]*r02;
  float v2 = Sc[0][2]*r00 + Sc[2][2]*r02;
  float v1 = Sc[0][1]*r00 + Sc[2][1]*r02;
  float a  = r00*v0 + r02*v2 + 0.3f;
  float bb = r11*v1 + r12*v2;
  float cc = r11*(Sc[1][1]*r11 + Sc[1][2]*r12) + r12*(Sc[2][1]*r11 + Sc[2][2]*r12) + 0.3f;
  float det = a*cc - bb*bb;
  float inv_det = 1.0f / fmaxf(det, 1e-12f);
  float Av = cc*inv_det, Bv = -bb*inv_det, Cv = a*inv_det;
  float u = fx*tcx*iz + cx;
  float v = fy*tcy*iz + cy;
  float op = opac[t];
  float op_eff = valid ? op : 0.0f;
  float tzo = valid ? tcz : 0.0f;
  float rx = -1.0f, ry = -1.0f;
  if (op_eff > (1.0f/255.0f)){
    float tau = logf(255.0f*op_eff);
    if (tau > 0.0f){
      rx = sqrtf(2.0f*tau*a) + 0.5f;
      ry = sqrtf(2.0f*tau*cc) + 0.5f;
    }
  }
  float key = valid ? tcz : __builtin_inff();

  keys[t] = key;
  __syncthreads();
  int rank = 0;
  for (int j=0;j<NG;j++){
    float kj = keys[j];
    rank += (kj < key) || (kj == key && j < t);
  }
  float4* wq = (float4*)wspq;
  float4 q0; q0.x = u;       q0.y = v;  q0.z = rx;       q0.w = ry;
  float4 q1; q1.x = 0.5f*Av; q1.y = Bv; q1.z = 0.5f*Cv;  q1.w = op_eff;
  float4 q2; q2.x = tzo;     q2.y = 0.f; q2.z = 0.f;     q2.w = 0.f;
  wq[rank*3+0] = q0;
  wq[rank*3+1] = q1;
  wq[rank*3+2] = q2;
  sidx[rank] = t;
}

// ---------------- kernel 1b: parallel gather of feats + weight transposes (105 blocks) ----------------
__global__ __launch_bounds__(256) void k_gather(
    const float* __restrict__ features,
    const float* __restrict__ w1,
    const float* __restrict__ w2,
    const float* __restrict__ w3,
    const int* __restrict__ sidx,
    unsigned short* __restrict__ wsf,
    unsigned short* __restrict__ wt1,
    unsigned short* __restrict__ wt2,
    unsigned short* __restrict__ wt3)
{
  const int bx = blockIdx.x, t = threadIdx.x;
  if (bx < 64){
    int c = bx*256 + t;
    int row = c >> 6, c4 = c & 63;
    int src = sidx[row];
    float4 f = ((const float4*)features)[src*(CF/4) + c4];
    unsigned int* dst = (unsigned int*)(wsf + row*CF + c4*4);
    dst[0] = (unsigned)f2bf(f.x) | ((unsigned)f2bf(f.y) << 16);
    dst[1] = (unsigned)f2bf(f.z) | ((unsigned)f2bf(f.w) << 16);
  } else if (bx < 96){
    int base = (bx-64)*1024 + t*4;
#pragma unroll
    for (int e=0;e<4;e++){
      int d = base + e;
      int j = d >> 8, k = d & 255;
      wt1[d] = f2bf(w1[k*128 + j]);
    }
  } else if (bx < 104){
    int base = (bx-96)*2048 + t*8;
#pragma unroll
    for (int e=0;e<8;e++){
      int d = base + e;
      int j = d >> 7, k = d & 127;
      wt2[d] = f2bf(w2[k*128 + j]);
    }
  } else {
    int base = t*8;
#pragma unroll
    for (int e=0;e<8;e++){
      int d = base + e;
      int j = d >> 7, k = d & 127;
      wt3[d] = (j < 12) ? f2bf(w3[k*12 + j]) : (unsigned short)0;
    }
  }
}

// ---------------- kernel 2: fused cull + render (MFMA splat, LDS-staged B) + depth + MLP ----------------
__global__ __launch_bounds__(256) void k_fused(
    const float* __restrict__ wspq,
    const unsigned short* __restrict__ wsf,
    const unsigned short* __restrict__ wt1,
    const unsigned short* __restrict__ wt2,
    const unsigned short* __restrict__ wt3,
    const float* __restrict__ b1,
    const float* __restrict__ b2,
    const float* __restrict__ b3,
    float* __restrict__ out,
    float* __restrict__ dep,
    float* __restrict__ seg)
{
  __shared__ __align__(16) unsigned char smem[64*AST*2 + 17408 + 1296];
  unsigned short* sh_A = (unsigned short*)smem;
  unsigned char* X = smem + 64*AST*2;
  float* c_u    = (float*)X;
  float* c_v    = c_u + 256;
  float* c_hA   = c_u + 512;
  float* c_Bq   = c_u + 768;
  float* c_hC   = c_u + 1024;
  float* c_op   = c_u + 1280;
  float* c_tz   = c_u + 1536;
  float* chprod = c_u + 1792;
  unsigned short* stage = (unsigned short*)X;
  unsigned short* sh_B  = (unsigned short*)X;
  unsigned char* tail = smem + 64*AST*2 + 17408;
  float* depch = (float*)tail;
  unsigned char* act_idx = tail + 1024;
  int* wcnt = (int*)(tail + 1280);

  const int t = threadIdx.x;
  const int lane = t & 63;
  const int wvi = t >> 6;
  const int y  = blockIdx.x / TILES_X;
  const int x0 = (blockIdx.x % TILES_X) * 64;

  act_idx[t] = 0;
  const float4* wq = (const float4*)wspq;
  float4 q0 = wq[t*3+0];
  bool pred = (q0.z > 0.0f)
      && (q0.x + q0.z >= (float)x0 + 0.5f)
      && (q0.x - q0.z <= (float)x0 + 63.5f)
      && (fabsf(q0.y - ((float)y + 0.5f)) <= q0.w);
  unsigned long long m = __ballot(pred);
  if (lane == 0) wcnt[wvi] = __popcll(m);
  __syncthreads();
  int base = 0;
#pragma unroll
  for (int i=0;i<4;i++) base += (i < wvi) ? wcnt[i] : 0;
  const int nact = wcnt[0]+wcnt[1]+wcnt[2]+wcnt[3];
  if (pred){
    int pos = base + __popcll(m & ((1ull << lane) - 1ull));
    float4 q1 = wq[t*3+1];
    float4 q2 = wq[t*3+2];
    act_idx[pos] = (unsigned char)t;
    c_u[pos]  = q0.x;  c_v[pos]  = q0.y;
    c_hA[pos] = q1.x;  c_Bq[pos] = q1.y;  c_hC[pos] = q1.z;
    c_op[pos] = q1.w;  c_tz[pos] = q2.x;
  }
  __syncthreads();

  const int per8 = ((((nact + 3) >> 2) + 7) & ~7);
  const int n0 = wvi * per8;
  const int n1 = (nact < n0 + per8) ? nact : (n0 + per8);
  const float px = (float)(x0 + lane) + 0.5f;
  const float py = (float)y + 0.5f;

  const int ln  = lane & 15;
  const int kq8 = (lane >> 4) * 8;
  const int rq  = (lane >> 4) * 4;
  const int cb0 = wvi * 64;
  const int la = lane & 7, lb = lane >> 3;
  const int kchunks = (nact + 31) >> 5;

  uint4 cur[4], nxt[4];
  if (kchunks > 0){
#pragma unroll
    for (int g=0; g<4; g++){
      int kk = lb + 8*g;
      cur[g] = *(const uint4*)(wsf + (int)act_idx[kk]*CF + cb0 + la*8);
    }
  }

  {
    float prod = 1.0f;
    for (int ng = n0; ng < n0 + per8; ng += 8){
      union { unsigned short s[8]; uint4 v4; } alp;
#pragma unroll
      for (int e=0;e<8;e++){
        int n = ng + e;
        float al = 0.0f;
        if (n < n1){
          float dx = px - c_u[n], dy = py - c_v[n];
          float q = c_hA[n]*dx*dx + c_Bq[n]*dx*dy + c_hC[n]*dy*dy;
          al = fminf(0.99f, c_op[n]*__expf(fminf(-q, 0.0f)));
          if (al < (1.0f/255.0f)) al = 0.0f;
        }
        alp.s[e] = f2bf(al);
        prod *= 1.0f - bf2f(alp.s[e]);
      }
      *((uint4*)&sh_A[lane*AST + ng]) = alp.v4;
    }
    chprod[t] = prod;
  }
  __syncthreads();

  {
    float T = 1.0f;
#pragma unroll
    for (int c=0;c<4;c++) if (c < wvi) T *= chprod[c*64 + lane];
    float dacc = 0.0f;
    for (int ng = n0; ng < n0 + per8; ng += 8){
      union { unsigned short s[8]; uint4 v4; } ap, wp;
      ap.v4 = *((const uint4*)&sh_A[lane*AST + ng]);
#pragma unroll
      for (int e=0;e<8;e++){
        float al = bf2f(ap.s[e]);
        float wgt = T * al;
        T *= 1.0f - al;
        wp.s[e] = f2bf(wgt);
        int n = ng + e;
        if (n < n1) dacc += wgt * c_tz[n];
      }
      *((uint4*)&sh_A[lane*AST + ng]) = wp.v4;
    }
    depch[t] = dacc;
  }
  __syncthreads();

  unsigned short* stW = stage + wvi*2048;
  const int xw = (la & 3) << 3;

  f32x4 acc[4][4];
#pragma unroll
  for (int mt=0;mt<4;mt++)
#pragma unroll
    for (int nt=0;nt<4;nt++){
      f32x4 z = {0.f,0.f,0.f,0.f};
      acc[mt][nt] = z;
    }
  for (int kb=0; kb<kchunks; kb++){
#pragma unroll
    for (int g=0; g<4; g++){
      const unsigned short* s = (const unsigned short*)&cur[g];
      int colw = (lb + 8*g) ^ xw;
#pragma unroll
      for (int i=0;i<8;i++)
        stW[(la*8 + i)*32 + colw] = s[i];
    }
    if (kb+1 < kchunks){
#pragma unroll
      for (int g=0; g<4; g++){
        int kk = (kb+1)*32 + lb + 8*g;
        nxt[g] = *(const uint4*)(wsf + (int)act_idx[kk]*CF + cb0 + la*8);
      }
    }
    int k0 = kb*32;
    s16x8 bfr[4];
#pragma unroll
    for (int nt=0;nt<4;nt++){
      int chl = nt*16 + ln;
      int colr = kq8 ^ (((chl >> 3) & 3) << 3);
      bfr[nt] = *(const s16x8*)(stW + chl*32 + colr);
    }
#pragma unroll
    for (int mt=0;mt<4;mt++){
      s16x8 afr = *(const s16x8*)(&sh_A[(mt*16 + ln)*AST + k0 + kq8]);
#pragma unroll
      for (int nt=0;nt<4;nt++)
        acc[mt][nt] = __builtin_amdgcn_mfma_f32_16x16x32_bf16(afr, bfr[nt], acc[mt][nt], 0, 0, 0);
    }
    if (kb+1 < kchunks){
#pragma unroll
      for (int g=0; g<4; g++) cur[g] = nxt[g];
    }
  }
  __syncthreads();

#pragma unroll
  for (int mt=0;mt<4;mt++)
#pragma unroll
    for (int nt=0;nt<4;nt++)
#pragma unroll
      for (int r=0;r<4;r++){
        int row = mt*16 + rq + r;
        int col = cb0 + nt*16 + ln;
        sh_A[row*AST + col] = f2bf(acc[mt][nt][r]);
      }
  __syncthreads();

  const int n0m = wvi * 32;
  f32x4 acc1[4][2];
#pragma unroll
  for (int nn=0;nn<2;nn++){
    float bv = b1[n0m + nn*16 + ln];
    f32x4 b4 = {bv,bv,bv,bv};
#pragma unroll
    for (int mt=0;mt<4;mt++) acc1[mt][nn] = b4;
  }
#pragma unroll
  for (int k0=0;k0<256;k0+=32){
    s16x8 bfr0 = *(const s16x8*)(wt1 + (n0m + 0*16 + ln)*256 + k0 + kq8);
    s16x8 bfr1 = *(const s16x8*)(wt1 + (n0m + 1*16 + ln)*256 + k0 + kq8);
#pragma unroll
    for (int mt=0;mt<4;mt++){
      s16x8 afr = *(const s16x8*)(&sh_A[(mt*16 + ln)*AST + k0 + kq8]);
      acc1[mt][0] = __builtin_amdgcn_mfma_f32_16x16x32_bf16(afr, bfr0, acc1[mt][0], 0, 0, 0);
      acc1[mt][1] = __builtin_amdgcn_mfma_f32_16x16x32_bf16(afr, bfr1, acc1[mt][1], 0, 0, 0);
    }
  }
#pragma unroll
  for (int mt=0;mt<4;mt++)
#pragma unroll
    for (int nn=0;nn<2;nn++)
#pragma unroll
      for (int r=0;r<4;r++){
        int mrow = mt*16 + rq + r;
        int ncol = n0m + nn*16 + ln;
        sh_B[mrow*BST + ncol] = f2bf(fmaxf(acc1[mt][nn][r], 0.0f));
      }
  __syncthreads();

  f32x4 acc2[4][2];
#pragma unroll
  for (int nn=0;nn<2;nn++){
    float bv = b2[n0m + nn*16 + ln];
    f32x4 b4 = {bv,bv,bv,bv};
#pragma unroll
    for (int mt=0;mt<4;mt++) acc2[mt][nn] = b4;
  }
#pragma unroll
  for (int k0=0;k0<128;k0+=32){
    s16x8 bfr0 = *(const s16x8*)(wt2 + (n0m + 0*16 + ln)*128 + k0 + kq8);
    s16x8 bfr1 = *(const s16x8*)(wt2 + (n0m + 1*16 + ln)*128 + k0 + kq8);
#pragma unroll
    for (int mt=0;mt<4;mt++){
      s16x8 afr = *(const s16x8*)(&sh_B[(mt*16 + ln)*BST + k0 + kq8]);
      acc2[mt][0] = __builtin_amdgcn_mfma_f32_16x16x32_bf16(afr, bfr0, acc2[mt][0], 0, 0, 0);
      acc2[mt][1] = __builtin_amdgcn_mfma_f32_16x16x32_bf16(afr, bfr1, acc2[mt][1], 0, 0, 0);
    }
  }
  __syncthreads();
#pragma unroll
  for (int mt=0;mt<4;mt++)
#pragma unroll
    for (int nn=0;nn<2;nn++)
#pragma unroll
      for (int r=0;r<4;r++){
        int mrow = mt*16 + rq + r;
        int ncol = n0m + nn*16 + ln;
        sh_B[mrow*BST + ncol] = f2bf(fmaxf(acc2[mt][nn][r], 0.0f));
      }
  __syncthreads();

  const size_t Pbase = (size_t)(y*WW + x0);
  f32x4 acc3;
  {
    float bv = (ln < 12) ? b3[ln] : 0.0f;
    f32x4 b4 = {bv,bv,bv,bv};
    acc3 = b4;
  }
#pragma unroll
  for (int k0=0;k0<128;k0+=32){
    s16x8 afr = *(const s16x8*)(&sh_B[(wvi*16 + ln)*BST + k0 + kq8]);
    s16x8 bfr = *(const s16x8*)(wt3 + ln*128 + k0 + kq8);
    acc3 = __builtin_amdgcn_mfma_f32_16x16x32_bf16(afr, bfr, acc3, 0, 0, 0);
  }
  if (ln < 12){
#pragma unroll
    for (int r=0;r<4;r++){
      int mrow = wvi*16 + rq + r;
      seg[(Pbase + mrow)*12 + ln] = acc3[r];
    }
  }

  if (wvi == 0){
    float d = depch[lane] + depch[64+lane] + depch[128+lane] + depch[192+lane];
    dep[y*WW + x0 + lane] = fminf(fmaxf(d, 0.0f), FARV);
  }

  {
    const int pxb = wvi*16;
    for (int i=0;i<16;i++){
      int pix = pxb + i;
      uint2 dv = *(const uint2*)(&sh_A[pix*AST + lane*4]);
      f32x4 o;
      o[0] = bf2f((unsigned short)(dv.x & 0xffffu));
      o[1] = bf2f((unsigned short)(dv.x >> 16));
      o[2] = bf2f((unsigned short)(dv.y & 0xffffu));
      o[3] = bf2f((unsigned short)(dv.y >> 16));
      __builtin_nontemporal_store(o, (f32x4*)(&out[(Pbase + pix)*CF + lane*4]));
    }
  }
}

extern "C" void kernel_launch(void* const* d_in, const int* in_sizes, int n_in,
                              void* d_out, int out_size, void* d_ws, size_t ws_size,
                              hipStream_t stream) {
  (void)in_sizes; (void)n_in; (void)out_size; (void)ws_size;
  const float* means3d  = (const float*)d_in[0];
  const float* features = (const float*)d_in[1];
  const float* opac     = (const float*)d_in[2];
  const float* scales   = (const float*)d_in[3];
  const float* rots     = (const float*)d_in[4];
  const float* camK     = (const float*)d_in[5];
  const float* camP     = (const float*)d_in[6];
  const float* w1       = (const float*)d_in[7];
  const float* b1       = (const float*)d_in[8];
  const float* w2       = (const float*)d_in[9];
  const float* b2       = (const float*)d_in[10];
  const float* w3       = (const float*)d_in[11];
  const float* b3       = (const float*)d_in[12];

  char* ws = (char*)d_ws;
  float*          wspq = (float*)ws;                       // [256][12] f32 = 12288 B
  int*            sidx = (int*)(ws + 12288);               // 1024 B
  unsigned short* wsf  = (unsigned short*)(ws + 13312);    // sorted feats [g][ch] bf16 = 131072 B
  unsigned short* wt1  = (unsigned short*)(ws + 144384);   // 128x256 bf16 = 65536 B
  unsigned short* wt2  = (unsigned short*)(ws + 209920);   // 128x128 bf16 = 32768 B
  unsigned short* wt3  = (unsigned short*)(ws + 242688);   // 16x128 bf16 = 4096 B

  float* out = (float*)d_out;
  float* dep = out + (size_t)HH*WW*CF;
  float* seg = dep + (size_t)HH*WW;

  k_proj<<<1, 256, 0, stream>>>(means3d, opac, scales, rots, camK, camP, wspq, sidx);
  k_gather<<<105, 256, 0, stream>>>(features, w1, w2, w3, sidx, wsf, wt1, wt2, wt3);
  k_fused<<<HH*TILES_X, 256, 0, stream>>>(wspq, wsf, wt1, wt2, wt3, b1, b2, b3, out, dep, seg);
}